// Round 9
// baseline (280.812 us; speedup 1.0000x reference)
//
#include <hip/hip_runtime.h>
#include <stdint.h>

#define D_MODEL 768
#define SEQ     2048
#define BATCH   2
#define NHEAD   12
#define DHEAD   64
#define MROWS   (BATCH * SEQ)          // 4096

typedef __bf16 bf16x8 __attribute__((ext_vector_type(8)));
typedef float  f32x4  __attribute__((ext_vector_type(4)));
typedef float  f32x16 __attribute__((ext_vector_type(16)));
typedef unsigned short u16;
typedef u16 u16x4 __attribute__((ext_vector_type(4)));
typedef u16 u16x8 __attribute__((ext_vector_type(8)));
typedef uint32_t u32;

__device__ __forceinline__ u16 f32_to_bf16(float x) {
    u32 u = __float_as_uint(x);
    u32 r = (u + 0x7FFFu + ((u >> 16) & 1u)) >> 16;
    return (u16)r;
}
__device__ __forceinline__ float bf16_to_f32(u16 h) {
    return __uint_as_float(((u32)h) << 16);
}
__device__ __forceinline__ void split2(float x, u16 &hi, u16 &lo) {
    hi = f32_to_bf16(x);
    lo = f32_to_bf16(x - bf16_to_f32(hi));
}
// truncating pack: (bf16(b)<<16)|bf16(a) in ONE v_perm_b32
__device__ __forceinline__ u32 pack2t(float a, float b) {
    return __builtin_amdgcn_perm(__float_as_uint(b), __float_as_uint(a), 0x07060302u);
}

__device__ __forceinline__ void stage16(const u16* g, const u16* l) {
    __builtin_amdgcn_global_load_lds(
        (const __attribute__((address_space(1))) u32*)g,
        (__attribute__((address_space(3))) u32*)l,
        16, 0, 0);
}

// ---------------------------------------------------------------------------
// LDS XOR-swizzle (T2, rule #21 both-sides): tiles are [rows][32] u16, row
// stride 64B. physical chunk col = logical col ^ ((row>>1)&3).
// For global_load_lds staging (B, and mode-3 A): LDS dest linear, GLOBAL
// source chunk pre-permuted (SRC_C8). For reg-staged A (fused X-split): the
// swizzle goes directly on the ds_write address. Read side: RD_C8.
// Verified round-1: frag-read conflicts eliminated.
// ---------------------------------------------------------------------------
#define SRC_C8(lane)  ((((lane) & 3) ^ (((lane) >> 3) & 3)) * 8)
#define RD_C8(quad, l16) (((quad) ^ (((l16) >> 1) & 3)) * 8)

// Q scale: 1/sqrt(64) * log2(e)  (attention works in exp2 domain)
#define QSCALE 0.1803368801111204f
// fixed softmax shift: p = 2^(s - 20)
#define MSHIFT 20.0f

// ---------------------------------------------------------------------------
// prep_all (round-9: X-split REMOVED — fused into gemm3 A-staging):
//   [0, 2304)   : W transpose+split (flattened 24x24x4)
//   [2304, 2320): mask -> bias
// ---------------------------------------------------------------------------
__global__ void prep_all(const float* __restrict__ Wq, const float* __restrict__ Wk,
                         const float* __restrict__ Wv, const float* __restrict__ Wo,
                         u16* __restrict__ wtbase,
                         const int* __restrict__ Mask, float* __restrict__ BiasM)
{
    __shared__ float tile[32][33];
    const int bx = blockIdx.x;
    if (bx < 2304) {
        int r = bx;
        int w = r / 576; r %= 576;
        int ky = r / 24, nx = r % 24;
        const float* W = (w == 0) ? Wq : (w == 1) ? Wk : (w == 2) ? Wv : Wo;
        const size_t WP = (size_t)D_MODEL * D_MODEL;
        u16* th = wtbase + (size_t)w * 2 * WP;
        u16* tl = th + WP;
        const int tx = threadIdx.x & 31, ty = threadIdx.x >> 5;
        const int n0 = nx * 32, k0 = ky * 32;
        #pragma unroll
        for (int rr = 0; rr < 4; ++rr) {
            int kk = k0 + ty + rr * 8;
            tile[ty + rr * 8][tx] = W[(size_t)kk * D_MODEL + n0 + tx];
        }
        __syncthreads();
        #pragma unroll
        for (int rr = 0; rr < 4; ++rr) {
            int n = n0 + ty + rr * 8;
            float val = tile[tx][ty + rr * 8];
            u16 h, l; split2(val, h, l);
            th[(size_t)n * D_MODEL + k0 + tx] = h;
            tl[(size_t)n * D_MODEL + k0 + tx] = l;
        }
    } else {
        int i = (bx - 2304) * 256 + threadIdx.x;
        BiasM[i] = (Mask[i] == 0) ? -3e38f : -MSHIFT;
    }
}

// ---------------------------------------------------------------------------
// gemm3: C[4096,768] = A @ B + bias with split bf16 hi/lo planes.
// Tile 128x64, grid (32,12,z), round-5 single-buffer loop (best measured:
// 71us QKV; dbuf/counted-vmcnt/64x64 all regressed — small-K shape is
// amortization-bound, occupancy 23-50% all equal).
// Round-9: A-staging FUSED X-split (mode != 3): reads f32 X directly
// (same bytes as hi+lo planes), splits in-registers, swizzled ds_write
// (write-side lanes hit 8 distinct bank quads — conflict-free). Kills
// prep_all's entire 75MB X round-trip. mode==3 keeps plane staging (CTX).
// ---------------------------------------------------------------------------
__global__ __launch_bounds__(256, 4) void gemm3(
    const u16* __restrict__ Ah, const u16* __restrict__ Al,
    const float* __restrict__ AF0, const float* __restrict__ AF1,
    const float* __restrict__ AF2,
    const u16* __restrict__ Bh0, const u16* __restrict__ Bl0,
    const u16* __restrict__ Bh1, const u16* __restrict__ Bl1,
    const u16* __restrict__ Bh2, const u16* __restrict__ Bl2,
    const float* __restrict__ bias0, const float* __restrict__ bias1,
    const float* __restrict__ bias2,
    u16* __restrict__ Qhl, u16* __restrict__ Khl, u16* __restrict__ Vt,
    float* __restrict__ Out, int mode)
{
    const int z = (mode == 3) ? 3 : (int)blockIdx.z;
    const u16 *GBh, *GBl; const float* Bias; const float* AF;
    if (z == 1)      { GBh = Bh1; GBl = Bl1; Bias = bias1; AF = AF1; }
    else if (z == 2) { GBh = Bh2; GBl = Bl2; Bias = bias2; AF = AF2; }
    else             { GBh = Bh0; GBl = Bl0; Bias = bias0; AF = AF0; }

    const int m0 = blockIdx.x * 128;
    const int n0 = blockIdx.y * 64;
    const int tid  = threadIdx.x;
    const int wave = tid >> 6, lane = tid & 63;
    const int quad = lane >> 4, l16 = lane & 15;
    const int wm = wave & 1, wn = wave >> 1;

    __shared__ u16 sAh[128 * 32];
    __shared__ u16 sAl[128 * 32];
    __shared__ u16 sBh[64 * 32];
    __shared__ u16 sBl[64 * 32];

    const int srow = lane >> 2;            // 0..15
    const int sc8  = SRC_C8(lane);         // swizzled source column chunk
    const int rc8  = RD_C8(quad, l16);     // swizzled read column chunk

    // fused-split A addressing: thread covers row=tid>>1, chunks c0,c0+1
    const int arow = tid >> 1;             // 0..127
    const int ac0  = (tid & 1) * 2;        // chunk pair base (0 or 2)
    const int aswz = (arow >> 1) & 3;      // write-side swizzle term

    f32x4 acc[4][2] = {};

    for (int k0 = 0; k0 < D_MODEL; k0 += 32) {
        // B staging: global_load_lds from pre-split W planes (pre-swizzled src)
        {
            int row = wave * 16 + srow;
            size_t gb = (size_t)(n0 + row) * D_MODEL + k0 + sc8;
            int ldst = (wave * 16) * 32;
            stage16(&GBh[gb], &sBh[ldst]);
            stage16(&GBl[gb], &sBl[ldst]);
        }
        // A staging
        if (mode == 3) {
            #pragma unroll
            for (int i = 0; i < 2; ++i) {
                int row = wave * 32 + i * 16 + srow;
                size_t ga = (size_t)(m0 + row) * D_MODEL + k0 + sc8;
                int ldst = (wave * 32 + i * 16) * 32;
                stage16(&Ah[ga], &sAh[ldst]);
                stage16(&Al[ga], &sAl[ldst]);
            }
        } else {
            // fused X-split: f32 -> hi/lo in regs -> swizzled ds_write_b128
            const float4* src = reinterpret_cast<const float4*>(
                &AF[(size_t)(m0 + arow) * D_MODEL + k0 + ac0 * 8]);
            float4 f0 = src[0], f1 = src[1], f2 = src[2], f3 = src[3];
            u16x8 h0, l0, h1, l1;
            {
                u16 h, l;
                split2(f0.x, h, l); h0[0] = h; l0[0] = l;
                split2(f0.y, h, l); h0[1] = h; l0[1] = l;
                split2(f0.z, h, l); h0[2] = h; l0[2] = l;
                split2(f0.w, h, l); h0[3] = h; l0[3] = l;
                split2(f1.x, h, l); h0[4] = h; l0[4] = l;
                split2(f1.y, h, l); h0[5] = h; l0[5] = l;
                split2(f1.z, h, l); h0[6] = h; l0[6] = l;
                split2(f1.w, h, l); h0[7] = h; l0[7] = l;
                split2(f2.x, h, l); h1[0] = h; l1[0] = l;
                split2(f2.y, h, l); h1[1] = h; l1[1] = l;
                split2(f2.z, h, l); h1[2] = h; l1[2] = l;
                split2(f2.w, h, l); h1[3] = h; l1[3] = l;
                split2(f3.x, h, l); h1[4] = h; l1[4] = l;
                split2(f3.y, h, l); h1[5] = h; l1[5] = l;
                split2(f3.z, h, l); h1[6] = h; l1[6] = l;
                split2(f3.w, h, l); h1[7] = h; l1[7] = l;
            }
            const int off0 = arow * 32 + ((ac0 ^ aswz) * 8);
            const int off1 = arow * 32 + (((ac0 + 1) ^ aswz) * 8);
            *reinterpret_cast<u16x8*>(&sAh[off0]) = h0;
            *reinterpret_cast<u16x8*>(&sAl[off0]) = l0;
            *reinterpret_cast<u16x8*>(&sAh[off1]) = h1;
            *reinterpret_cast<u16x8*>(&sAl[off1]) = l1;
        }
        __syncthreads();

        bf16x8 afh[4], afl[4], bfh[2], bfl[2];
        #pragma unroll
        for (int t = 0; t < 4; ++t) {
            int ar = wm * 64 + t * 16 + l16;
            afh[t] = *reinterpret_cast<const bf16x8*>(&sAh[ar * 32 + rc8]);
            afl[t] = *reinterpret_cast<const bf16x8*>(&sAl[ar * 32 + rc8]);
        }
        #pragma unroll
        for (int t = 0; t < 2; ++t) {
            int bc = wn * 32 + t * 16 + l16;
            bfh[t] = *reinterpret_cast<const bf16x8*>(&sBh[bc * 32 + rc8]);
            bfl[t] = *reinterpret_cast<const bf16x8*>(&sBl[bc * 32 + rc8]);
        }
        #pragma unroll
        for (int mt = 0; mt < 4; ++mt) {
            #pragma unroll
            for (int nt = 0; nt < 2; ++nt) {
                f32x4 a = acc[mt][nt];
                a = __builtin_amdgcn_mfma_f32_16x16x32_bf16(afh[mt], bfh[nt], a, 0, 0, 0);
                a = __builtin_amdgcn_mfma_f32_16x16x32_bf16(afh[mt], bfl[nt], a, 0, 0, 0);
                a = __builtin_amdgcn_mfma_f32_16x16x32_bf16(afl[mt], bfh[nt], a, 0, 0, 0);
                acc[mt][nt] = a;
            }
        }
        __syncthreads();
    }

    #pragma unroll
    for (int nt = 0; nt < 2; ++nt) {
        int n = n0 + wn * 32 + nt * 16 + l16;
        float bv = Bias[n];
        #pragma unroll
        for (int mt = 0; mt < 4; ++mt) {
            #pragma unroll
            for (int r = 0; r < 4; ++r) {
                int m = m0 + wm * 64 + mt * 16 + quad * 4 + r;
                float v = acc[mt][nt][r] + bv;
                if (mode == 3) {
                    Out[(size_t)m * D_MODEL + n] = v;
                } else {
                    int b = m >> 11, s = m & (SEQ - 1);
                    int h = n >> 6, d = n & 63;
                    size_t bh = (size_t)(b * NHEAD + h);
                    if (z == 0) {
                        u16 hi, lo; split2(v * QSCALE, hi, lo);  // 1/8 * log2e
                        u16* base = &Qhl[(bh * SEQ + s) * 128];
                        base[d] = hi; base[d + 64] = lo;
                    } else if (z == 1) {
                        u16 hi, lo; split2(v, hi, lo);
                        u16* base = &Khl[(bh * SEQ + s) * 128];
                        base[d] = hi; base[d + 64] = lo;
                    } else {
                        Vt[(bh * DHEAD + d) * SEQ + s] = f32_to_bf16(v);
                    }
                }
            }
        }
    }
}

// ---------------------------------------------------------------------------
// Flash attention, S^T form, exp2 fixed-max softmax, q-tile 128.
// Round-5 (kept, best): 32x32x16 MFMA shape; permlane32_swap half-exchange
// for P -> PV-B-operand; setprio around MFMA clusters; dbuf 48KB; XCD remap.
// ---------------------------------------------------------------------------
__global__ __launch_bounds__(256, 3) void attn_kernel(
    const u16* __restrict__ Qhl, const u16* __restrict__ Khl, const u16* __restrict__ Vt,
    const float* __restrict__ BiasM, float* __restrict__ Opart,
    float* __restrict__ Lpart)
{
    // XCD remap: phys block p runs work w = (p%8)*96 + p/8 (bijective, 768%8==0).
    const int flat = blockIdx.x;
    const int wk   = (flat & 7) * 96 + (flat >> 3);
    const int qt   = wk & 15;             // 0..15  (fastest within group)
    const int grp  = wk >> 4;             // 0..47
    const int bh   = grp % 24;
    const int half = grp / 24;            // 0..1
    const int b    = bh / NHEAD;
    const int tid  = threadIdx.x;
    const int wave = tid >> 6, lane = tid & 63;
    const int l32  = lane & 31;           // q within wave / row within tile
    const int hi5  = lane >> 5;           // k-half selector
    const int xorv = (l32 >> 1) & 3;      // read-side swizzle term

    __shared__ u16 sK[2][4 * 2048];       // [64][32] x (hi-d0,hi-d1,lo-d0,lo-d1)
    __shared__ u16 sV[2][2 * 2048];       // [64 d][32 s] x 2

    // Q B-frags: q = qt*128 + wave*32 + l32; frag ds: d = ds*16 + hi5*8 + j
    const u16* qbase = &Qhl[((size_t)bh * SEQ + qt * 128 + wave * 32 + l32) * 128];
    bf16x8 qh[4], ql[4];
    #pragma unroll
    for (int ds = 0; ds < 4; ++ds) {
        qh[ds] = *reinterpret_cast<const bf16x8*>(&qbase[ds * 16 + hi5 * 8]);
        ql[ds] = *reinterpret_cast<const bf16x8*>(&qbase[64 + ds * 16 + hi5 * 8]);
    }

    // ones A-frag (bf16 1.0 x8) for the l row-sum MFMA
    union OU { u16 u[8]; bf16x8 v; } onesu;
    #pragma unroll
    for (int j = 0; j < 8; ++j) onesu.u[j] = 0x3F80;
    const bf16x8 ones = onesu.v;

    f32x16 oacc[2] = {};                  // O^T tiles d 0-31 / 32-63
    f32x16 lacc = {};                     // l in row 0 (all rows equal)

    const float* biasb = &BiasM[b * SEQ];
    const int strow = wave * 16 + (lane >> 2);
    const int stc8  = SRC_C8(lane);       // swizzled source column chunk
    const u16* kgb = &Khl[(size_t)bh * SEQ * 128];
    const u16* vgb = &Vt[(size_t)bh * DHEAD * SEQ];

    const int kvbeg = half * (SEQ / 2);

    // prologue: stage tile 0 into buffer 0
    #pragma unroll
    for (int j = 0; j < 4; ++j)
        stage16(&kgb[(size_t)(kvbeg + strow) * 128 + j * 32 + stc8],
                &sK[0][j * 2048 + wave * 512]);
    #pragma unroll
    for (int j = 0; j < 2; ++j)
        stage16(&vgb[(size_t)strow * SEQ + kvbeg + j * 32 + stc8],
                &sV[0][j * 2048 + wave * 512]);

    for (int it = 0; it < 16; ++it) {
        const int kv0 = kvbeg + it * 64;
        asm volatile("s_waitcnt vmcnt(0)" ::: "memory");
        __syncthreads();

        if (it + 1 < 16) {
            const int kvn = kv0 + 64;
            u16* dK = sK[(it + 1) & 1];
            u16* dV = sV[(it + 1) & 1];
            #pragma unroll
            for (int j = 0; j < 4; ++j)
                stage16(&kgb[(size_t)(kvn + strow) * 128 + j * 32 + stc8],
                        &dK[j * 2048 + wave * 512]);
            #pragma unroll
            for (int j = 0; j < 2; ++j)
                stage16(&vgb[(size_t)strow * SEQ + kvn + j * 32 + stc8],
                        &dV[j * 2048 + wave * 512]);
        }
        const u16* cK = sK[it & 1];
        const u16* cV = sV[it & 1];

        // per kv-tile: QK^T (12 mfma) -> exp2 -> pack; P kept as 8 u32/lane
        u32 pk[2][8];
        #pragma unroll
        for (int t = 0; t < 2; ++t) {
            f32x16 s;
            #pragma unroll
            for (int g = 0; g < 4; ++g) {
                float4 b4 = *reinterpret_cast<const float4*>(
                    &biasb[kv0 + t * 32 + 8 * g + 4 * hi5]);
                s[4 * g + 0] = b4.x; s[4 * g + 1] = b4.y;
                s[4 * g + 2] = b4.z; s[4 * g + 3] = b4.w;
            }
            const int rowb = (t * 32 + l32) * 32;
            __builtin_amdgcn_s_setprio(1);
            #pragma unroll
            for (int ds = 0; ds < 4; ++ds) {
                const int c8  = ((((ds & 1) * 2 + hi5) ^ xorv) * 8);
                const int off = (ds >> 1) * 2048 + rowb + c8;
                bf16x8 kh = *reinterpret_cast<const bf16x8*>(&cK[off]);
                bf16x8 kl = *reinterpret_cast<const bf16x8*>(&cK[4096 + off]);
                s = __builtin_amdgcn_mfma_f32_32x32x16_bf16(kh, qh[ds], s, 0, 0, 0);
                s = __builtin_amdgcn_mfma_f32_32x32x16_bf16(kh, ql[ds], s, 0, 0, 0);
                s = __builtin_amdgcn_mfma_f32_32x32x16_bf16(kl, qh[ds], s, 0, 0, 0);
            }
            __builtin_amdgcn_s_setprio(0);
            #pragma unroll
            for (int m = 0; m < 8; ++m)
                pk[t][m] = pack2t(exp2f(s[2 * m]), exp2f(s[2 * m + 1]));
        }

        // half-exchange: build 4 PV B-frags (kv slices of 16) from pk
        union FU { u32 u[4]; bf16x8 v; } fr[4];
        #pragma unroll
        for (int t = 0; t < 2; ++t) {
            u32 a0 = pk[t][0], b0 = pk[t][2];
            u32 a1 = pk[t][1], b1 = pk[t][3];
            u32 a2 = pk[t][4], b2 = pk[t][6];
            u32 a3 = pk[t][5], b3 = pk[t][7];
            asm volatile("v_permlane32_swap_b32 %0, %1" : "+v"(a0), "+v"(b0));
            asm volatile("v_permlane32_swap_b32 %0, %1" : "+v"(a1), "+v"(b1));
            asm volatile("v_permlane32_swap_b32 %0, %1" : "+v"(a2), "+v"(b2));
            asm volatile("v_permlane32_swap_b32 %0, %1" : "+v"(a3), "+v"(b3));
            fr[2 * t].u[0] = a0; fr[2 * t].u[1] = a1;
            fr[2 * t].u[2] = b0; fr[2 * t].u[3] = b1;
            fr[2 * t + 1].u[0] = a2; fr[2 * t + 1].u[1] = a3;
            fr[2 * t + 1].u[2] = b2; fr[2 * t + 1].u[3] = b3;
        }

        // O^T += V^T · P^T  (A = V^T frag, B = P frag), + l row-sum
        __builtin_amdgcn_s_setprio(1);
        #pragma unroll
        for (int dt = 0; dt < 2; ++dt) {
            const int drow = (dt * 32 + l32) * 32;
            #pragma unroll
            for (int sl = 0; sl < 4; ++sl) {
                const int c8  = ((((sl & 1) * 2 + hi5) ^ xorv) * 8);
                const int off = (sl >> 1) * 2048 + drow + c8;
                bf16x8 vb = *reinterpret_cast<const bf16x8*>(&cV[off]);
                oacc[dt] = __builtin_amdgcn_mfma_f32_32x32x16_bf16(vb, fr[sl].v, oacc[dt], 0, 0, 0);
            }
        }
        #pragma unroll
        for (int sl = 0; sl < 4; ++sl)
            lacc = __builtin_amdgcn_mfma_f32_32x32x16_bf16(ones, fr[sl].v, lacc, 0, 0, 0);
        __builtin_amdgcn_s_setprio(0);
        // no trailing barrier: next iteration's barrier protects the buffers
    }

    {
        size_t rowb = ((size_t)(half * (BATCH * NHEAD) + bh)) * SEQ
                    + qt * 128 + wave * 32 + l32;
        float* ob = &Opart[rowb * 64];
        #pragma unroll
        for (int dt = 0; dt < 2; ++dt) {
            #pragma unroll
            for (int g = 0; g < 4; ++g) {
                f32x4 o4 = { oacc[dt][4 * g + 0], oacc[dt][4 * g + 1],
                             oacc[dt][4 * g + 2], oacc[dt][4 * g + 3] };
                *reinterpret_cast<f32x4*>(&ob[dt * 32 + 8 * g + 4 * hi5]) = o4;
            }
        }
        if (lane < 32) Lpart[rowb] = lacc[0];   // row 0: l(q=l32)
    }
}

// ---------------------------------------------------------------------------
// attn_combine: merge 2 kv-half partials (same fixed scale -> plain sums)
// ---------------------------------------------------------------------------
__global__ void attn_combine(const float* __restrict__ Opart,
                             const float* __restrict__ Lpart,
                             u16* __restrict__ CTXh, u16* __restrict__ CTXl)
{
    const int NROW = BATCH * NHEAD * SEQ;              // 49152
    int t = blockIdx.x * 256 + threadIdx.x;
    int row = t >> 4;
    int d0 = (t & 15) << 2;
    float inv = 1.f / (Lpart[row] + Lpart[NROW + row]);
    f32x4 O0 = *reinterpret_cast<const f32x4*>(&Opart[(size_t)row * 64 + d0]);
    f32x4 O1 = *reinterpret_cast<const f32x4*>(&Opart[((size_t)NROW + row) * 64 + d0]);
    int bh = row >> 11, q = row & (SEQ - 1);
    int b = bh / NHEAD, h = bh % NHEAD;
    size_t off = ((size_t)(b * SEQ + q)) * D_MODEL + h * DHEAD + d0;
    u16x4 h4, l4;
    #pragma unroll
    for (int j = 0; j < 4; ++j) {
        float val = (O0[j] + O1[j]) * inv;
        u16 hi, lo; split2(val, hi, lo);
        h4[j] = hi; l4[j] = lo;
    }
    *reinterpret_cast<u16x4*>(&CTXh[off]) = h4;
    *reinterpret_cast<u16x4*>(&CTXl[off]) = l4;
}

// ---------------------------------------------------------------------------
extern "C" void kernel_launch(void* const* d_in, const int* in_sizes, int n_in,
                              void* d_out, int out_size, void* d_ws, size_t ws_size,
                              hipStream_t stream)
{
    const float* query = (const float*)d_in[0];
    const float* key   = (const float*)d_in[1];
    const float* value = (const float*)d_in[2];
    const int*   mask  = (const int*)d_in[3];
    const float* Wq = (const float*)d_in[4];
    const float* bq = (const float*)d_in[5];
    const float* Wk = (const float*)d_in[6];
    const float* bk = (const float*)d_in[7];
    const float* Wv = (const float*)d_in[8];
    const float* bv = (const float*)d_in[9];
    const float* Wo = (const float*)d_in[10];
    const float* bo = (const float*)d_in[11];

    char* ws = (char*)d_ws;
    const size_t P2  = (size_t)MROWS * D_MODEL * 2;       // X plane: 6.29 MB
    const size_t WP2 = (size_t)D_MODEL * D_MODEL * 2;     // W plane: 1.18 MB

    // X-plane region retained only as scratch for Opart/CTX aliases.
    u16* Xbase = (u16*)ws;
    u16* Xh_q = Xbase;                       u16* Xl_q = (u16*)((char*)Xh_q + P2);
    u16* Xh_k = (u16*)((char*)Xbase + 2*P2);

    char* wtb = ws + 6 * P2;
    u16* Wh_q = (u16*)wtb;                   u16* Wl_q = (u16*)(wtb + WP2);
    u16* Wh_k = (u16*)(wtb + 2*WP2);         u16* Wl_k = (u16*)(wtb + 3*WP2);
    u16* Wh_v = (u16*)(wtb + 4*WP2);         u16* Wl_v = (u16*)(wtb + 5*WP2);
    u16* Wh_o = (u16*)(wtb + 6*WP2);         u16* Wl_o = (u16*)(wtb + 7*WP2);

    char* qb = wtb + 8 * WP2;
    const size_t QK_BYTES = (size_t)BATCH * NHEAD * SEQ * 128 * 2;  // 12.58 MB
    u16* QhlBuf = (u16*)qb;
    u16* KhlBuf = (u16*)(qb + QK_BYTES);
    u16* VtBuf  = (u16*)(qb + 2 * QK_BYTES);              // 6.29 MB

    char* tail = qb + 2 * QK_BYTES + QK_BYTES / 2;
    float* BiasM = (float*)tail;                           // 16 KB
    float* Lpart = (float*)(tail + 16384);                 // 384 KB

    float* Opart = (float*)Xh_k;          // aliases X region (now pure scratch)
    u16* CTXh = Xh_q; u16* CTXl = Xl_q;   // reuse X region for context planes

    float* out = (float*)d_out;
    dim3 blk(256, 1, 1);

    prep_all<<<dim3(2320), blk, 0, stream>>>(
        Wq, Wk, Wv, Wo, (u16*)wtb, mask, BiasM);

    gemm3<<<dim3(32, 12, 3), blk, 0, stream>>>(
        nullptr, nullptr, query, key, value,
        Wh_q, Wl_q, Wh_k, Wl_k, Wh_v, Wl_v,
        bq, bk, bv, QhlBuf, KhlBuf, VtBuf, nullptr, 0);

    attn_kernel<<<dim3(768), blk, 0, stream>>>(
        QhlBuf, KhlBuf, VtBuf, BiasM, Opart, Lpart);

    attn_combine<<<dim3(3072), blk, 0, stream>>>(Opart, Lpart, CTXh, CTXl);

    gemm3<<<dim3(32, 12, 1), blk, 0, stream>>>(
        CTXh, CTXl, nullptr, nullptr, nullptr,
        Wh_o, Wl_o, nullptr, nullptr, nullptr, nullptr,
        bo, nullptr, nullptr, nullptr, nullptr, nullptr, out, 3);
}

// Round 10
// 264.873 us; speedup vs baseline: 1.0602x; 1.0602x over previous
//
#include <hip/hip_runtime.h>
#include <stdint.h>

#define D_MODEL 768
#define SEQ     2048
#define BATCH   2
#define NHEAD   12
#define DHEAD   64
#define MROWS   (BATCH * SEQ)          // 4096

typedef __bf16 bf16x8 __attribute__((ext_vector_type(8)));
typedef float  f32x4  __attribute__((ext_vector_type(4)));
typedef float  f32x16 __attribute__((ext_vector_type(16)));
typedef unsigned short u16;
typedef u16 u16x4 __attribute__((ext_vector_type(4)));
typedef uint32_t u32;

__device__ __forceinline__ u16 f32_to_bf16(float x) {
    u32 u = __float_as_uint(x);
    u32 r = (u + 0x7FFFu + ((u >> 16) & 1u)) >> 16;
    return (u16)r;
}
__device__ __forceinline__ float bf16_to_f32(u16 h) {
    return __uint_as_float(((u32)h) << 16);
}
__device__ __forceinline__ void split2(float x, u16 &hi, u16 &lo) {
    hi = f32_to_bf16(x);
    lo = f32_to_bf16(x - bf16_to_f32(hi));
}
// truncating pack: (bf16(b)<<16)|bf16(a) in ONE v_perm_b32
__device__ __forceinline__ u32 pack2t(float a, float b) {
    return __builtin_amdgcn_perm(__float_as_uint(b), __float_as_uint(a), 0x07060302u);
}

__device__ __forceinline__ void stage16(const u16* g, const u16* l) {
    __builtin_amdgcn_global_load_lds(
        (const __attribute__((address_space(1))) u32*)g,
        (__attribute__((address_space(3))) u32*)l,
        16, 0, 0);
}

// ---------------------------------------------------------------------------
// LDS XOR-swizzle (T2, rule #21 both-sides): tiles are [rows][32] u16, row
// stride 64B. global_load_lds writes linearly, so the LDS dest stays linear,
// the GLOBAL source column chunk is permuted on the write side, and the same
// involution is applied on the read address:
//   physical chunk col = logical col ^ ((row>>1)&3)
// write side (lane l covers row l>>2, chunk l&3; row bases ==0 mod 8):
//   src chunk col = (l&3) ^ ((l>>3)&3)
// read side (row = base + l16, base ==0 mod 8):
//   read chunk col = quad ^ ((l16>>1)&3)
// Verified round-1: frag-read conflicts eliminated.
// ---------------------------------------------------------------------------
#define SRC_C8(lane)  ((((lane) & 3) ^ (((lane) >> 3) & 3)) * 8)
#define RD_C8(quad, l16) (((quad) ^ (((l16) >> 1) & 3)) * 8)

// Q scale: 1/sqrt(64) * log2(e)  (attention works in exp2 domain)
#define QSCALE 0.1803368801111204f
// fixed softmax shift: p = 2^(s - 20)
#define MSHIFT 20.0f

// ---------------------------------------------------------------------------
// prep_all: merged prep kernels (block ranges):
//   [0, 9216)        : X split  (t = bx/3072)
//   [9216, 11520)    : W transpose+split (flattened 24x24x4)
//   [11520, 11536)   : mask -> bias
// (round-9 fusion of X-split into gemm3 regressed +25us: reg-staged split
//  sits on the barrier critical path vs async global_load_lds — reverted.)
// ---------------------------------------------------------------------------
__global__ void prep_all(const float* __restrict__ q, const float* __restrict__ k,
                         const float* __restrict__ v, u16* __restrict__ xbase,
                         const float* __restrict__ Wq, const float* __restrict__ Wk,
                         const float* __restrict__ Wv, const float* __restrict__ Wo,
                         u16* __restrict__ wtbase,
                         const int* __restrict__ Mask, float* __restrict__ BiasM)
{
    __shared__ float tile[32][33];
    const int bx = blockIdx.x;
    if (bx < 9216) {
        const int t = bx / 3072;
        const float* src = (t == 0) ? q : (t == 1) ? k : v;
        const size_t P = (size_t)MROWS * D_MODEL;
        u16* xh = xbase + (size_t)t * 2 * P;
        u16* xl = xh + P;
        size_t idx = ((size_t)(bx % 3072) * 256 + threadIdx.x) * 4;
        float4 val = *reinterpret_cast<const float4*>(&src[idx]);
        float vv[4] = {val.x, val.y, val.z, val.w};
        u16x4 h4, l4;
        #pragma unroll
        for (int j = 0; j < 4; ++j) { u16 h, l; split2(vv[j], h, l); h4[j] = h; l4[j] = l; }
        *reinterpret_cast<u16x4*>(&xh[idx]) = h4;
        *reinterpret_cast<u16x4*>(&xl[idx]) = l4;
    } else if (bx < 11520) {
        int r = bx - 9216;
        int w = r / 576; r %= 576;
        int ky = r / 24, nx = r % 24;
        const float* W = (w == 0) ? Wq : (w == 1) ? Wk : (w == 2) ? Wv : Wo;
        const size_t WP = (size_t)D_MODEL * D_MODEL;
        u16* th = wtbase + (size_t)w * 2 * WP;
        u16* tl = th + WP;
        const int tx = threadIdx.x & 31, ty = threadIdx.x >> 5;
        const int n0 = nx * 32, k0 = ky * 32;
        #pragma unroll
        for (int rr = 0; rr < 4; ++rr) {
            int kk = k0 + ty + rr * 8;
            tile[ty + rr * 8][tx] = W[(size_t)kk * D_MODEL + n0 + tx];
        }
        __syncthreads();
        #pragma unroll
        for (int rr = 0; rr < 4; ++rr) {
            int n = n0 + ty + rr * 8;
            float val = tile[tx][ty + rr * 8];
            u16 h, l; split2(val, h, l);
            th[(size_t)n * D_MODEL + k0 + tx] = h;
            tl[(size_t)n * D_MODEL + k0 + tx] = l;
        }
    } else {
        int i = (bx - 11520) * 256 + threadIdx.x;
        BiasM[i] = (Mask[i] == 0) ? -3e38f : -MSHIFT;
    }
}

// ---------------------------------------------------------------------------
// gemm3: C[4096,768] = A @ B + bias with pre-split bf16 hi/lo planes.
// Tile 128x64; grid (m=32, n=12, z). Round-5 single-buffer loop — BEST
// measured for QKV (71us). Dbuf (r6), counted-vmcnt (r8), 64x64 (r7), fused
// X-split (r9) all regressed; small-K shape is amortization-bound here.
// LDS tiles swizzled (SRC_C8/RD_C8) -> conflict-free ds_read_b128.
// ---------------------------------------------------------------------------
__global__ __launch_bounds__(256, 4) void gemm3(
    const u16* __restrict__ Ah0, const u16* __restrict__ Al0,
    const u16* __restrict__ Ah1, const u16* __restrict__ Al1,
    const u16* __restrict__ Ah2, const u16* __restrict__ Al2,
    const u16* __restrict__ Bh0, const u16* __restrict__ Bl0,
    const u16* __restrict__ Bh1, const u16* __restrict__ Bl1,
    const u16* __restrict__ Bh2, const u16* __restrict__ Bl2,
    const float* __restrict__ bias0, const float* __restrict__ bias1,
    const float* __restrict__ bias2,
    u16* __restrict__ Qhl, u16* __restrict__ Khl, u16* __restrict__ Vt,
    float* __restrict__ Out, int mode)
{
    const int z = (mode == 3) ? 3 : (int)blockIdx.z;
    const u16 *GAh, *GAl, *GBh, *GBl; const float* Bias;
    if (z == 1)      { GAh = Ah1; GAl = Al1; GBh = Bh1; GBl = Bl1; Bias = bias1; }
    else if (z == 2) { GAh = Ah2; GAl = Al2; GBh = Bh2; GBl = Bl2; Bias = bias2; }
    else             { GAh = Ah0; GAl = Al0; GBh = Bh0; GBl = Bl0; Bias = bias0; }

    const int m0 = blockIdx.x * 128;
    const int n0 = blockIdx.y * 64;
    const int tid  = threadIdx.x;
    const int wave = tid >> 6, lane = tid & 63;
    const int quad = lane >> 4, l16 = lane & 15;
    const int wm = wave & 1, wn = wave >> 1;

    __shared__ u16 sAh[128 * 32];
    __shared__ u16 sAl[128 * 32];
    __shared__ u16 sBh[64 * 32];
    __shared__ u16 sBl[64 * 32];

    const int srow = lane >> 2;            // 0..15
    const int sc8  = SRC_C8(lane);         // swizzled source column chunk
    const int rc8  = RD_C8(quad, l16);     // swizzled read column chunk

    f32x4 acc[4][2] = {};

    for (int k0 = 0; k0 < D_MODEL; k0 += 32) {
        {
            #pragma unroll
            for (int i = 0; i < 2; ++i) {
                int row = wave * 32 + i * 16 + srow;
                size_t ga = (size_t)(m0 + row) * D_MODEL + k0 + sc8;
                int ldst = (wave * 32 + i * 16) * 32;
                stage16(&GAh[ga], &sAh[ldst]);
                stage16(&GAl[ga], &sAl[ldst]);
            }
            int row = wave * 16 + srow;
            size_t gb = (size_t)(n0 + row) * D_MODEL + k0 + sc8;
            int ldst = (wave * 16) * 32;
            stage16(&GBh[gb], &sBh[ldst]);
            stage16(&GBl[gb], &sBl[ldst]);
        }
        asm volatile("s_waitcnt vmcnt(0)" ::: "memory");
        __syncthreads();

        bf16x8 afh[4], afl[4], bfh[2], bfl[2];
        #pragma unroll
        for (int t = 0; t < 4; ++t) {
            int ar = wm * 64 + t * 16 + l16;
            afh[t] = *reinterpret_cast<const bf16x8*>(&sAh[ar * 32 + rc8]);
            afl[t] = *reinterpret_cast<const bf16x8*>(&sAl[ar * 32 + rc8]);
        }
        #pragma unroll
        for (int t = 0; t < 2; ++t) {
            int bc = wn * 32 + t * 16 + l16;
            bfh[t] = *reinterpret_cast<const bf16x8*>(&sBh[bc * 32 + rc8]);
            bfl[t] = *reinterpret_cast<const bf16x8*>(&sBl[bc * 32 + rc8]);
        }
        #pragma unroll
        for (int mt = 0; mt < 4; ++mt) {
            #pragma unroll
            for (int nt = 0; nt < 2; ++nt) {
                f32x4 a = acc[mt][nt];
                a = __builtin_amdgcn_mfma_f32_16x16x32_bf16(afh[mt], bfh[nt], a, 0, 0, 0);
                a = __builtin_amdgcn_mfma_f32_16x16x32_bf16(afh[mt], bfl[nt], a, 0, 0, 0);
                a = __builtin_amdgcn_mfma_f32_16x16x32_bf16(afl[mt], bfh[nt], a, 0, 0, 0);
                acc[mt][nt] = a;
            }
        }
        __syncthreads();
    }

    #pragma unroll
    for (int nt = 0; nt < 2; ++nt) {
        int n = n0 + wn * 32 + nt * 16 + l16;
        float bv = Bias[n];
        #pragma unroll
        for (int mt = 0; mt < 4; ++mt) {
            #pragma unroll
            for (int r = 0; r < 4; ++r) {
                int m = m0 + wm * 64 + mt * 16 + quad * 4 + r;
                float v = acc[mt][nt][r] + bv;
                if (mode == 3) {
                    Out[(size_t)m * D_MODEL + n] = v;
                } else {
                    int b = m >> 11, s = m & (SEQ - 1);
                    int h = n >> 6, d = n & 63;
                    size_t bh = (size_t)(b * NHEAD + h);
                    if (z == 0) {
                        u16 hi, lo; split2(v * QSCALE, hi, lo);  // 1/8 * log2e
                        u16* base = &Qhl[(bh * SEQ + s) * 128];
                        base[d] = hi; base[d + 64] = lo;
                    } else if (z == 1) {
                        u16 hi, lo; split2(v, hi, lo);
                        u16* base = &Khl[(bh * SEQ + s) * 128];
                        base[d] = hi; base[d + 64] = lo;
                    } else {
                        Vt[(bh * DHEAD + d) * SEQ + s] = f32_to_bf16(v);
                    }
                }
            }
        }
    }
}

// ---------------------------------------------------------------------------
// gemm_out64: out-projection Out[4096,768] = CTX @ Wo + bo, tile 64x64.
// The 128x64 kernel at grid 384 = 1.5 blocks/CU is the most latency-starved
// dispatch in the pipeline. 64x64 -> grid (64,12) = 768 blocks = 3/CU (2x
// residency), LDS 16KB, VGPR ~40. Bit-identical results: the K-iteration
// order and per-output MFMA accumulate order are unchanged (round-7
// verified this tile geometry passes with identical absmax).
// ---------------------------------------------------------------------------
__global__ __launch_bounds__(256, 4) void gemm_out64(
    const u16* __restrict__ GAh, const u16* __restrict__ GAl,
    const u16* __restrict__ GBh, const u16* __restrict__ GBl,
    const float* __restrict__ Bias, float* __restrict__ Out)
{
    const int m0 = blockIdx.x * 64;
    const int n0 = blockIdx.y * 64;
    const int tid  = threadIdx.x;
    const int wave = tid >> 6, lane = tid & 63;
    const int quad = lane >> 4, l16 = lane & 15;
    const int wm = wave & 1, wn = wave >> 1;

    __shared__ u16 sAh[64 * 32];
    __shared__ u16 sAl[64 * 32];
    __shared__ u16 sBh[64 * 32];
    __shared__ u16 sBl[64 * 32];

    const int srow = lane >> 2;            // 0..15
    const int sc8  = SRC_C8(lane);
    const int rc8  = RD_C8(quad, l16);

    f32x4 acc[2][2] = {};

    for (int k0 = 0; k0 < D_MODEL; k0 += 32) {
        {
            int row = wave * 16 + srow;
            size_t ga = (size_t)(m0 + row) * D_MODEL + k0 + sc8;
            size_t gb = (size_t)(n0 + row) * D_MODEL + k0 + sc8;
            int ldst = (wave * 16) * 32;
            stage16(&GAh[ga], &sAh[ldst]);
            stage16(&GAl[ga], &sAl[ldst]);
            stage16(&GBh[gb], &sBh[ldst]);
            stage16(&GBl[gb], &sBl[ldst]);
        }
        asm volatile("s_waitcnt vmcnt(0)" ::: "memory");
        __syncthreads();

        bf16x8 afh[2], afl[2], bfh[2], bfl[2];
        #pragma unroll
        for (int t = 0; t < 2; ++t) {
            int ar = wm * 32 + t * 16 + l16;
            afh[t] = *reinterpret_cast<const bf16x8*>(&sAh[ar * 32 + rc8]);
            afl[t] = *reinterpret_cast<const bf16x8*>(&sAl[ar * 32 + rc8]);
        }
        #pragma unroll
        for (int t = 0; t < 2; ++t) {
            int bc = wn * 32 + t * 16 + l16;
            bfh[t] = *reinterpret_cast<const bf16x8*>(&sBh[bc * 32 + rc8]);
            bfl[t] = *reinterpret_cast<const bf16x8*>(&sBl[bc * 32 + rc8]);
        }
        #pragma unroll
        for (int mt = 0; mt < 2; ++mt) {
            #pragma unroll
            for (int nt = 0; nt < 2; ++nt) {
                f32x4 a = acc[mt][nt];
                a = __builtin_amdgcn_mfma_f32_16x16x32_bf16(afh[mt], bfh[nt], a, 0, 0, 0);
                a = __builtin_amdgcn_mfma_f32_16x16x32_bf16(afh[mt], bfl[nt], a, 0, 0, 0);
                a = __builtin_amdgcn_mfma_f32_16x16x32_bf16(afl[mt], bfh[nt], a, 0, 0, 0);
                acc[mt][nt] = a;
            }
        }
        __syncthreads();
    }

    #pragma unroll
    for (int nt = 0; nt < 2; ++nt) {
        int n = n0 + wn * 32 + nt * 16 + l16;
        float bv = Bias[n];
        #pragma unroll
        for (int mt = 0; mt < 2; ++mt) {
            #pragma unroll
            for (int r = 0; r < 4; ++r) {
                int m = m0 + wm * 32 + mt * 16 + quad * 4 + r;
                Out[(size_t)m * D_MODEL + n] = acc[mt][nt][r] + bv;
            }
        }
    }
}

// ---------------------------------------------------------------------------
// Flash attention, S^T form, exp2 fixed-max softmax, q-tile 128.
// Round-5 (kept, best): 32x32x16 MFMA shape; permlane32_swap half-exchange
// for P -> PV-B-operand; setprio around MFMA clusters; dbuf 48KB; XCD remap.
// ---------------------------------------------------------------------------
__global__ __launch_bounds__(256, 3) void attn_kernel(
    const u16* __restrict__ Qhl, const u16* __restrict__ Khl, const u16* __restrict__ Vt,
    const float* __restrict__ BiasM, float* __restrict__ Opart,
    float* __restrict__ Lpart)
{
    // XCD remap: phys block p runs work w = (p%8)*96 + p/8 (bijective, 768%8==0).
    const int flat = blockIdx.x;
    const int wk   = (flat & 7) * 96 + (flat >> 3);
    const int qt   = wk & 15;             // 0..15  (fastest within group)
    const int grp  = wk >> 4;             // 0..47
    const int bh   = grp % 24;
    const int half = grp / 24;            // 0..1
    const int b    = bh / NHEAD;
    const int tid  = threadIdx.x;
    const int wave = tid >> 6, lane = tid & 63;
    const int l32  = lane & 31;           // q within wave / row within tile
    const int hi5  = lane >> 5;           // k-half selector
    const int xorv = (l32 >> 1) & 3;      // read-side swizzle term

    __shared__ u16 sK[2][4 * 2048];       // [64][32] x (hi-d0,hi-d1,lo-d0,lo-d1)
    __shared__ u16 sV[2][2 * 2048];       // [64 d][32 s] x 2

    // Q B-frags: q = qt*128 + wave*32 + l32; frag ds: d = ds*16 + hi5*8 + j
    const u16* qbase = &Qhl[((size_t)bh * SEQ + qt * 128 + wave * 32 + l32) * 128];
    bf16x8 qh[4], ql[4];
    #pragma unroll
    for (int ds = 0; ds < 4; ++ds) {
        qh[ds] = *reinterpret_cast<const bf16x8*>(&qbase[ds * 16 + hi5 * 8]);
        ql[ds] = *reinterpret_cast<const bf16x8*>(&qbase[64 + ds * 16 + hi5 * 8]);
    }

    // ones A-frag (bf16 1.0 x8) for the l row-sum MFMA
    union OU { u16 u[8]; bf16x8 v; } onesu;
    #pragma unroll
    for (int j = 0; j < 8; ++j) onesu.u[j] = 0x3F80;
    const bf16x8 ones = onesu.v;

    f32x16 oacc[2] = {};                  // O^T tiles d 0-31 / 32-63
    f32x16 lacc = {};                     // l in row 0 (all rows equal)

    const float* biasb = &BiasM[b * SEQ];
    const int strow = wave * 16 + (lane >> 2);
    const int stc8  = SRC_C8(lane);       // swizzled source column chunk
    const u16* kgb = &Khl[(size_t)bh * SEQ * 128];
    const u16* vgb = &Vt[(size_t)bh * DHEAD * SEQ];

    const int kvbeg = half * (SEQ / 2);

    // prologue: stage tile 0 into buffer 0
    #pragma unroll
    for (int j = 0; j < 4; ++j)
        stage16(&kgb[(size_t)(kvbeg + strow) * 128 + j * 32 + stc8],
                &sK[0][j * 2048 + wave * 512]);
    #pragma unroll
    for (int j = 0; j < 2; ++j)
        stage16(&vgb[(size_t)strow * SEQ + kvbeg + j * 32 + stc8],
                &sV[0][j * 2048 + wave * 512]);

    for (int it = 0; it < 16; ++it) {
        const int kv0 = kvbeg + it * 64;
        asm volatile("s_waitcnt vmcnt(0)" ::: "memory");
        __syncthreads();

        if (it + 1 < 16) {
            const int kvn = kv0 + 64;
            u16* dK = sK[(it + 1) & 1];
            u16* dV = sV[(it + 1) & 1];
            #pragma unroll
            for (int j = 0; j < 4; ++j)
                stage16(&kgb[(size_t)(kvn + strow) * 128 + j * 32 + stc8],
                        &dK[j * 2048 + wave * 512]);
            #pragma unroll
            for (int j = 0; j < 2; ++j)
                stage16(&vgb[(size_t)strow * SEQ + kvn + j * 32 + stc8],
                        &dV[j * 2048 + wave * 512]);
        }
        const u16* cK = sK[it & 1];
        const u16* cV = sV[it & 1];

        // per kv-tile: QK^T (12 mfma) -> exp2 -> pack; P kept as 8 u32/lane
        u32 pk[2][8];
        #pragma unroll
        for (int t = 0; t < 2; ++t) {
            f32x16 s;
            #pragma unroll
            for (int g = 0; g < 4; ++g) {
                float4 b4 = *reinterpret_cast<const float4*>(
                    &biasb[kv0 + t * 32 + 8 * g + 4 * hi5]);
                s[4 * g + 0] = b4.x; s[4 * g + 1] = b4.y;
                s[4 * g + 2] = b4.z; s[4 * g + 3] = b4.w;
            }
            const int rowb = (t * 32 + l32) * 32;
            __builtin_amdgcn_s_setprio(1);
            #pragma unroll
            for (int ds = 0; ds < 4; ++ds) {
                const int c8  = ((((ds & 1) * 2 + hi5) ^ xorv) * 8);
                const int off = (ds >> 1) * 2048 + rowb + c8;
                bf16x8 kh = *reinterpret_cast<const bf16x8*>(&cK[off]);
                bf16x8 kl = *reinterpret_cast<const bf16x8*>(&cK[4096 + off]);
                s = __builtin_amdgcn_mfma_f32_32x32x16_bf16(kh, qh[ds], s, 0, 0, 0);
                s = __builtin_amdgcn_mfma_f32_32x32x16_bf16(kh, ql[ds], s, 0, 0, 0);
                s = __builtin_amdgcn_mfma_f32_32x32x16_bf16(kl, qh[ds], s, 0, 0, 0);
            }
            __builtin_amdgcn_s_setprio(0);
            #pragma unroll
            for (int m = 0; m < 8; ++m)
                pk[t][m] = pack2t(exp2f(s[2 * m]), exp2f(s[2 * m + 1]));
        }

        // half-exchange: build 4 PV B-frags (kv slices of 16) from pk
        union FU { u32 u[4]; bf16x8 v; } fr[4];
        #pragma unroll
        for (int t = 0; t < 2; ++t) {
            u32 a0 = pk[t][0], b0 = pk[t][2];
            u32 a1 = pk[t][1], b1 = pk[t][3];
            u32 a2 = pk[t][4], b2 = pk[t][6];
            u32 a3 = pk[t][5], b3 = pk[t][7];
            asm volatile("v_permlane32_swap_b32 %0, %1" : "+v"(a0), "+v"(b0));
            asm volatile("v_permlane32_swap_b32 %0, %1" : "+v"(a1), "+v"(b1));
            asm volatile("v_permlane32_swap_b32 %0, %1" : "+v"(a2), "+v"(b2));
            asm volatile("v_permlane32_swap_b32 %0, %1" : "+v"(a3), "+v"(b3));
            fr[2 * t].u[0] = a0; fr[2 * t].u[1] = a1;
            fr[2 * t].u[2] = b0; fr[2 * t].u[3] = b1;
            fr[2 * t + 1].u[0] = a2; fr[2 * t + 1].u[1] = a3;
            fr[2 * t + 1].u[2] = b2; fr[2 * t + 1].u[3] = b3;
        }

        // O^T += V^T · P^T  (A = V^T frag, B = P frag), + l row-sum
        __builtin_amdgcn_s_setprio(1);
        #pragma unroll
        for (int dt = 0; dt < 2; ++dt) {
            const int drow = (dt * 32 + l32) * 32;
            #pragma unroll
            for (int sl = 0; sl < 4; ++sl) {
                const int c8  = ((((sl & 1) * 2 + hi5) ^ xorv) * 8);
                const int off = (sl >> 1) * 2048 + drow + c8;
                bf16x8 vb = *reinterpret_cast<const bf16x8*>(&cV[off]);
                oacc[dt] = __builtin_amdgcn_mfma_f32_32x32x16_bf16(vb, fr[sl].v, oacc[dt], 0, 0, 0);
            }
        }
        #pragma unroll
        for (int sl = 0; sl < 4; ++sl)
            lacc = __builtin_amdgcn_mfma_f32_32x32x16_bf16(ones, fr[sl].v, lacc, 0, 0, 0);
        __builtin_amdgcn_s_setprio(0);
        // no trailing barrier: next iteration's barrier protects the buffers
    }

    {
        size_t rowb = ((size_t)(half * (BATCH * NHEAD) + bh)) * SEQ
                    + qt * 128 + wave * 32 + l32;
        float* ob = &Opart[rowb * 64];
        #pragma unroll
        for (int dt = 0; dt < 2; ++dt) {
            #pragma unroll
            for (int g = 0; g < 4; ++g) {
                f32x4 o4 = { oacc[dt][4 * g + 0], oacc[dt][4 * g + 1],
                             oacc[dt][4 * g + 2], oacc[dt][4 * g + 3] };
                *reinterpret_cast<f32x4*>(&ob[dt * 32 + 8 * g + 4 * hi5]) = o4;
            }
        }
        if (lane < 32) Lpart[rowb] = lacc[0];   // row 0: l(q=l32)
    }
}

// ---------------------------------------------------------------------------
// attn_combine: merge 2 kv-half partials (same fixed scale -> plain sums)
// ---------------------------------------------------------------------------
__global__ void attn_combine(const float* __restrict__ Opart,
                             const float* __restrict__ Lpart,
                             u16* __restrict__ CTXh, u16* __restrict__ CTXl)
{
    const int NROW = BATCH * NHEAD * SEQ;              // 49152
    int t = blockIdx.x * 256 + threadIdx.x;
    int row = t >> 4;
    int d0 = (t & 15) << 2;
    float inv = 1.f / (Lpart[row] + Lpart[NROW + row]);
    f32x4 O0 = *reinterpret_cast<const f32x4*>(&Opart[(size_t)row * 64 + d0]);
    f32x4 O1 = *reinterpret_cast<const f32x4*>(&Opart[((size_t)NROW + row) * 64 + d0]);
    int bh = row >> 11, q = row & (SEQ - 1);
    int b = bh / NHEAD, h = bh % NHEAD;
    size_t off = ((size_t)(b * SEQ + q)) * D_MODEL + h * DHEAD + d0;
    u16x4 h4, l4;
    #pragma unroll
    for (int j = 0; j < 4; ++j) {
        float val = (O0[j] + O1[j]) * inv;
        u16 hi, lo; split2(val, hi, lo);
        h4[j] = hi; l4[j] = lo;
    }
    *reinterpret_cast<u16x4*>(&CTXh[off]) = h4;
    *reinterpret_cast<u16x4*>(&CTXl[off]) = l4;
}

// ---------------------------------------------------------------------------
extern "C" void kernel_launch(void* const* d_in, const int* in_sizes, int n_in,
                              void* d_out, int out_size, void* d_ws, size_t ws_size,
                              hipStream_t stream)
{
    const float* query = (const float*)d_in[0];
    const float* key   = (const float*)d_in[1];
    const float* value = (const float*)d_in[2];
    const int*   mask  = (const int*)d_in[3];
    const float* Wq = (const float*)d_in[4];
    const float* bq = (const float*)d_in[5];
    const float* Wk = (const float*)d_in[6];
    const float* bk = (const float*)d_in[7];
    const float* Wv = (const float*)d_in[8];
    const float* bv = (const float*)d_in[9];
    const float* Wo = (const float*)d_in[10];
    const float* bo = (const float*)d_in[11];

    char* ws = (char*)d_ws;
    const size_t P2  = (size_t)MROWS * D_MODEL * 2;       // X plane: 6.29 MB
    const size_t WP2 = (size_t)D_MODEL * D_MODEL * 2;     // W plane: 1.18 MB

    u16* Xbase = (u16*)ws;                                 // 6 planes
    u16* Xh_q = Xbase;                       u16* Xl_q = (u16*)((char*)Xh_q + P2);
    u16* Xh_k = (u16*)((char*)Xbase + 2*P2); u16* Xl_k = (u16*)((char*)Xh_k + P2);
    u16* Xh_v = (u16*)((char*)Xbase + 4*P2); u16* Xl_v = (u16*)((char*)Xh_v + P2);

    char* wtb = ws + 6 * P2;
    u16* Wh_q = (u16*)wtb;                   u16* Wl_q = (u16*)(wtb + WP2);
    u16* Wh_k = (u16*)(wtb + 2*WP2);         u16* Wl_k = (u16*)(wtb + 3*WP2);
    u16* Wh_v = (u16*)(wtb + 4*WP2);         u16* Wl_v = (u16*)(wtb + 5*WP2);
    u16* Wh_o = (u16*)(wtb + 6*WP2);         u16* Wl_o = (u16*)(wtb + 7*WP2);

    char* qb = wtb + 8 * WP2;
    const size_t QK_BYTES = (size_t)BATCH * NHEAD * SEQ * 128 * 2;  // 12.58 MB
    u16* QhlBuf = (u16*)qb;
    u16* KhlBuf = (u16*)(qb + QK_BYTES);
    u16* VtBuf  = (u16*)(qb + 2 * QK_BYTES);              // 6.29 MB

    char* tail = qb + 2 * QK_BYTES + QK_BYTES / 2;
    float* BiasM = (float*)tail;                           // 16 KB
    float* Lpart = (float*)(tail + 16384);                 // 384 KB

    float* Opart = (float*)Xh_k;          // aliases planes dead after QKV GEMM
    u16* CTXh = Xh_q; u16* CTXl = Xl_q;   // reuse query planes

    float* out = (float*)d_out;
    dim3 blk(256, 1, 1);

    prep_all<<<dim3(11536), blk, 0, stream>>>(
        query, key, value, Xbase, Wq, Wk, Wv, Wo, (u16*)wtb, mask, BiasM);

    gemm3<<<dim3(32, 12, 3), blk, 0, stream>>>(
        Xh_q, Xl_q, Xh_k, Xl_k, Xh_v, Xl_v,
        Wh_q, Wl_q, Wh_k, Wl_k, Wh_v, Wl_v,
        bq, bk, bv, QhlBuf, KhlBuf, VtBuf, nullptr, 0);

    attn_kernel<<<dim3(768), blk, 0, stream>>>(
        QhlBuf, KhlBuf, VtBuf, BiasM, Opart, Lpart);

    attn_combine<<<dim3(3072), blk, 0, stream>>>(Opart, Lpart, CTXh, CTXl);

    gemm_out64<<<dim3(64, 12), blk, 0, stream>>>(
        CTXh, CTXl, Wh_o, Wl_o, bo, out);
}

// Round 11
// 260.860 us; speedup vs baseline: 1.0765x; 1.0154x over previous
//
#include <hip/hip_runtime.h>
#include <stdint.h>

#define D_MODEL 768
#define SEQ     2048
#define BATCH   2
#define NHEAD   12
#define DHEAD   64
#define MROWS   (BATCH * SEQ)          // 4096

typedef __bf16 bf16x8 __attribute__((ext_vector_type(8)));
typedef float  f32x4  __attribute__((ext_vector_type(4)));
typedef float  f32x16 __attribute__((ext_vector_type(16)));
typedef unsigned short u16;
typedef u16 u16x4 __attribute__((ext_vector_type(4)));
typedef uint32_t u32;

__device__ __forceinline__ u16 f32_to_bf16(float x) {
    u32 u = __float_as_uint(x);
    u32 r = (u + 0x7FFFu + ((u >> 16) & 1u)) >> 16;
    return (u16)r;
}
__device__ __forceinline__ float bf16_to_f32(u16 h) {
    return __uint_as_float(((u32)h) << 16);
}
__device__ __forceinline__ void split2(float x, u16 &hi, u16 &lo) {
    hi = f32_to_bf16(x);
    lo = f32_to_bf16(x - bf16_to_f32(hi));
}
// truncating pack: (bf16(b)<<16)|bf16(a) in ONE v_perm_b32
__device__ __forceinline__ u32 pack2t(float a, float b) {
    return __builtin_amdgcn_perm(__float_as_uint(b), __float_as_uint(a), 0x07060302u);
}

__device__ __forceinline__ void stage16(const u16* g, const u16* l) {
    __builtin_amdgcn_global_load_lds(
        (const __attribute__((address_space(1))) u32*)g,
        (__attribute__((address_space(3))) u32*)l,
        16, 0, 0);
}

// ---------------------------------------------------------------------------
// LDS XOR-swizzle (T2, rule #21 both-sides): tiles are [rows][32] u16, row
// stride 64B. global_load_lds writes linearly, so the LDS dest stays linear,
// the GLOBAL source column chunk is permuted on the write side, and the same
// involution is applied on the read address:
//   physical chunk col = logical col ^ ((row>>1)&3)
// write side (lane l covers row base+(l>>2), chunk l&3; row bases ==0 mod 8):
//   src chunk col = (l&3) ^ ((l>>3)&3)
// read side (row = base + l16, base ==0 mod 8):
//   read chunk col = quad ^ ((l16>>1)&3)
// Verified round-1: frag-read conflicts eliminated.
// ---------------------------------------------------------------------------
#define SRC_C8(lane)  ((((lane) & 3) ^ (((lane) >> 3) & 3)) * 8)
#define RD_C8(quad, l16) (((quad) ^ (((l16) >> 1) & 3)) * 8)

// Q scale: 1/sqrt(64) * log2(e)  (attention works in exp2 domain)
#define QSCALE 0.1803368801111204f
// fixed softmax shift: p = 2^(s - 20)
#define MSHIFT 20.0f

// ---------------------------------------------------------------------------
// prep_all: merged prep kernels (block ranges):
//   [0, 9216)        : X split  (t = bx/3072)
//   [9216, 11520)    : W transpose+split (flattened 24x24x4)
//   [11520, 11536)   : mask -> bias
// ---------------------------------------------------------------------------
__global__ void prep_all(const float* __restrict__ q, const float* __restrict__ k,
                         const float* __restrict__ v, u16* __restrict__ xbase,
                         const float* __restrict__ Wq, const float* __restrict__ Wk,
                         const float* __restrict__ Wv, const float* __restrict__ Wo,
                         u16* __restrict__ wtbase,
                         const int* __restrict__ Mask, float* __restrict__ BiasM)
{
    __shared__ float tile[32][33];
    const int bx = blockIdx.x;
    if (bx < 9216) {
        const int t = bx / 3072;
        const float* src = (t == 0) ? q : (t == 1) ? k : v;
        const size_t P = (size_t)MROWS * D_MODEL;
        u16* xh = xbase + (size_t)t * 2 * P;
        u16* xl = xh + P;
        size_t idx = ((size_t)(bx % 3072) * 256 + threadIdx.x) * 4;
        float4 val = *reinterpret_cast<const float4*>(&src[idx]);
        float vv[4] = {val.x, val.y, val.z, val.w};
        u16x4 h4, l4;
        #pragma unroll
        for (int j = 0; j < 4; ++j) { u16 h, l; split2(vv[j], h, l); h4[j] = h; l4[j] = l; }
        *reinterpret_cast<u16x4*>(&xh[idx]) = h4;
        *reinterpret_cast<u16x4*>(&xl[idx]) = l4;
    } else if (bx < 11520) {
        int r = bx - 9216;
        int w = r / 576; r %= 576;
        int ky = r / 24, nx = r % 24;
        const float* W = (w == 0) ? Wq : (w == 1) ? Wk : (w == 2) ? Wv : Wo;
        const size_t WP = (size_t)D_MODEL * D_MODEL;
        u16* th = wtbase + (size_t)w * 2 * WP;
        u16* tl = th + WP;
        const int tx = threadIdx.x & 31, ty = threadIdx.x >> 5;
        const int n0 = nx * 32, k0 = ky * 32;
        #pragma unroll
        for (int rr = 0; rr < 4; ++rr) {
            int kk = k0 + ty + rr * 8;
            tile[ty + rr * 8][tx] = W[(size_t)kk * D_MODEL + n0 + tx];
        }
        __syncthreads();
        #pragma unroll
        for (int rr = 0; rr < 4; ++rr) {
            int n = n0 + ty + rr * 8;
            float val = tile[tx][ty + rr * 8];
            u16 h, l; split2(val, h, l);
            th[(size_t)n * D_MODEL + k0 + tx] = h;
            tl[(size_t)n * D_MODEL + k0 + tx] = l;
        }
    } else {
        int i = (bx - 11520) * 256 + threadIdx.x;
        BiasM[i] = (Mask[i] == 0) ? -3e38f : -MSHIFT;
    }
}

// ---------------------------------------------------------------------------
// gemm3 (QKV): C[4096,768] = A @ B + bias, pre-split bf16 hi/lo planes.
// Round-11: tile 64x192 (was 128x64). Rounds 5-8 proved the inner schedule
// is NOT the limit (occ 23-50%, dbuf, counted-vmcnt all 71-86us, MfmaUtil
// ~22%): the saturated resource is the L2-miss path — with 12 n-blocks the
// 12.6MB/z A panels were re-read 12x = 453MB from L3 (invisible in
// FETCH_SIZE, which is HBM-only). n-tile 192 -> 4 n-blocks (4x A re-read),
// and the 1-D XCD-bijective Y-FASTEST work order puts the 4 ny-siblings of
// each m-tile consecutively on ONE XCD: per-iter A-chunks are L3-fetched
// once and L2-hit 3x -> effective A L3 traffic ~38MB. Numerics unchanged
// (same K order, same 3-MFMA accumulate sequence). launch_bounds(256,2):
// VGPR cap 256 >> ~160 live (round-3 spill lesson). LDS 32KB.
// ---------------------------------------------------------------------------
__global__ __launch_bounds__(256, 2) void gemm3(
    const u16* __restrict__ Ah0, const u16* __restrict__ Al0,
    const u16* __restrict__ Ah1, const u16* __restrict__ Al1,
    const u16* __restrict__ Ah2, const u16* __restrict__ Al2,
    const u16* __restrict__ Bh0, const u16* __restrict__ Bl0,
    const u16* __restrict__ Bh1, const u16* __restrict__ Bl1,
    const u16* __restrict__ Bh2, const u16* __restrict__ Bl2,
    const float* __restrict__ bias0, const float* __restrict__ bias1,
    const float* __restrict__ bias2,
    u16* __restrict__ Qhl, u16* __restrict__ Khl, u16* __restrict__ Vt)
{
    // 1-D grid 768. XCD-bijective: wk = (p%8)*96 + p/8 (768%8==0).
    // Decompose wk: z = wk/256; r = wk%256; mx = r>>2; ny = r&3 (y-fastest).
    const int p  = blockIdx.x;
    const int wk = (p & 7) * 96 + (p >> 3);
    const int z  = wk / 256;
    const int r  = wk % 256;
    const int mx = r >> 2;
    const int ny = r & 3;

    const u16 *GAh, *GAl, *GBh, *GBl; const float* Bias;
    if (z == 1)      { GAh = Ah1; GAl = Al1; GBh = Bh1; GBl = Bl1; Bias = bias1; }
    else if (z == 2) { GAh = Ah2; GAl = Al2; GBh = Bh2; GBl = Bl2; Bias = bias2; }
    else             { GAh = Ah0; GAl = Al0; GBh = Bh0; GBl = Bl0; Bias = bias0; }

    const int m0 = mx * 64;
    const int n0 = ny * 192;
    const int tid  = threadIdx.x;
    const int wave = tid >> 6, lane = tid & 63;
    const int quad = lane >> 4, l16 = lane & 15;
    const int wm = wave & 1, wn = wave >> 1;

    __shared__ u16 sAh[64 * 32];
    __shared__ u16 sAl[64 * 32];
    __shared__ u16 sBh[192 * 32];
    __shared__ u16 sBl[192 * 32];

    const int srow = lane >> 2;            // 0..15
    const int sc8  = SRC_C8(lane);         // swizzled source column chunk
    const int rc8  = RD_C8(quad, l16);     // swizzled read column chunk

    f32x4 acc[2][6] = {};

    for (int k0 = 0; k0 < D_MODEL; k0 += 32) {
        {
            // A: 64 rows (1 sweep)
            int row = wave * 16 + srow;
            size_t ga = (size_t)(m0 + row) * D_MODEL + k0 + sc8;
            int ldst = (wave * 16) * 32;
            stage16(&GAh[ga], &sAh[ldst]);
            stage16(&GAl[ga], &sAl[ldst]);
            // B: 192 rows (3 sweeps). Row bases j*64+wave*16 ==0 mod 8, so
            // SRC_C8(lane) is the correct source swizzle for every sweep.
            #pragma unroll
            for (int j = 0; j < 3; ++j) {
                int brow = j * 64 + wave * 16 + srow;
                size_t gb = (size_t)(n0 + brow) * D_MODEL + k0 + sc8;
                int bdst = (j * 64 + wave * 16) * 32;
                stage16(&GBh[gb], &sBh[bdst]);
                stage16(&GBl[gb], &sBl[bdst]);
            }
        }
        asm volatile("s_waitcnt vmcnt(0)" ::: "memory");
        __syncthreads();

        bf16x8 afh[2], afl[2], bfh[6], bfl[6];
        #pragma unroll
        for (int t = 0; t < 2; ++t) {
            int ar = wm * 32 + t * 16 + l16;
            afh[t] = *reinterpret_cast<const bf16x8*>(&sAh[ar * 32 + rc8]);
            afl[t] = *reinterpret_cast<const bf16x8*>(&sAl[ar * 32 + rc8]);
        }
        #pragma unroll
        for (int t = 0; t < 6; ++t) {
            int bc = wn * 96 + t * 16 + l16;
            bfh[t] = *reinterpret_cast<const bf16x8*>(&sBh[bc * 32 + rc8]);
            bfl[t] = *reinterpret_cast<const bf16x8*>(&sBl[bc * 32 + rc8]);
        }
        #pragma unroll
        for (int mt = 0; mt < 2; ++mt) {
            #pragma unroll
            for (int nt = 0; nt < 6; ++nt) {
                f32x4 a = acc[mt][nt];
                a = __builtin_amdgcn_mfma_f32_16x16x32_bf16(afh[mt], bfh[nt], a, 0, 0, 0);
                a = __builtin_amdgcn_mfma_f32_16x16x32_bf16(afh[mt], bfl[nt], a, 0, 0, 0);
                a = __builtin_amdgcn_mfma_f32_16x16x32_bf16(afl[mt], bfh[nt], a, 0, 0, 0);
                acc[mt][nt] = a;
            }
        }
        __syncthreads();
    }

    #pragma unroll
    for (int nt = 0; nt < 6; ++nt) {
        int n = n0 + wn * 96 + nt * 16 + l16;
        float bv = Bias[n];
        #pragma unroll
        for (int mt = 0; mt < 2; ++mt) {
            #pragma unroll
            for (int rr = 0; rr < 4; ++rr) {
                int m = m0 + wm * 32 + mt * 16 + quad * 4 + rr;
                float v = acc[mt][nt][rr] + bv;
                int b = m >> 11, s = m & (SEQ - 1);
                int h = n >> 6, d = n & 63;
                size_t bh = (size_t)(b * NHEAD + h);
                if (z == 0) {
                    u16 hi, lo; split2(v * QSCALE, hi, lo);  // 1/8 * log2e
                    u16* base = &Qhl[(bh * SEQ + s) * 128];
                    base[d] = hi; base[d + 64] = lo;
                } else if (z == 1) {
                    u16 hi, lo; split2(v, hi, lo);
                    u16* base = &Khl[(bh * SEQ + s) * 128];
                    base[d] = hi; base[d + 64] = lo;
                } else {
                    Vt[(bh * DHEAD + d) * SEQ + s] = f32_to_bf16(v);
                }
            }
        }
    }
}

// ---------------------------------------------------------------------------
// gemm_out64: out-projection Out[4096,768] = CTX @ Wo + bo, tile 64x64.
// Grid (64,12) = 768 blocks = 3/CU. Kept from round 10 (measured neutral).
// ---------------------------------------------------------------------------
__global__ __launch_bounds__(256, 4) void gemm_out64(
    const u16* __restrict__ GAh, const u16* __restrict__ GAl,
    const u16* __restrict__ GBh, const u16* __restrict__ GBl,
    const float* __restrict__ Bias, float* __restrict__ Out)
{
    const int m0 = blockIdx.x * 64;
    const int n0 = blockIdx.y * 64;
    const int tid  = threadIdx.x;
    const int wave = tid >> 6, lane = tid & 63;
    const int quad = lane >> 4, l16 = lane & 15;
    const int wm = wave & 1, wn = wave >> 1;

    __shared__ u16 sAh[64 * 32];
    __shared__ u16 sAl[64 * 32];
    __shared__ u16 sBh[64 * 32];
    __shared__ u16 sBl[64 * 32];

    const int srow = lane >> 2;            // 0..15
    const int sc8  = SRC_C8(lane);
    const int rc8  = RD_C8(quad, l16);

    f32x4 acc[2][2] = {};

    for (int k0 = 0; k0 < D_MODEL; k0 += 32) {
        {
            int row = wave * 16 + srow;
            size_t ga = (size_t)(m0 + row) * D_MODEL + k0 + sc8;
            size_t gb = (size_t)(n0 + row) * D_MODEL + k0 + sc8;
            int ldst = (wave * 16) * 32;
            stage16(&GAh[ga], &sAh[ldst]);
            stage16(&GAl[ga], &sAl[ldst]);
            stage16(&GBh[gb], &sBh[ldst]);
            stage16(&GBl[gb], &sBl[ldst]);
        }
        asm volatile("s_waitcnt vmcnt(0)" ::: "memory");
        __syncthreads();

        bf16x8 afh[2], afl[2], bfh[2], bfl[2];
        #pragma unroll
        for (int t = 0; t < 2; ++t) {
            int ar = wm * 32 + t * 16 + l16;
            afh[t] = *reinterpret_cast<const bf16x8*>(&sAh[ar * 32 + rc8]);
            afl[t] = *reinterpret_cast<const bf16x8*>(&sAl[ar * 32 + rc8]);
        }
        #pragma unroll
        for (int t = 0; t < 2; ++t) {
            int bc = wn * 32 + t * 16 + l16;
            bfh[t] = *reinterpret_cast<const bf16x8*>(&sBh[bc * 32 + rc8]);
            bfl[t] = *reinterpret_cast<const bf16x8*>(&sBl[bc * 32 + rc8]);
        }
        #pragma unroll
        for (int mt = 0; mt < 2; ++mt) {
            #pragma unroll
            for (int nt = 0; nt < 2; ++nt) {
                f32x4 a = acc[mt][nt];
                a = __builtin_amdgcn_mfma_f32_16x16x32_bf16(afh[mt], bfh[nt], a, 0, 0, 0);
                a = __builtin_amdgcn_mfma_f32_16x16x32_bf16(afh[mt], bfl[nt], a, 0, 0, 0);
                a = __builtin_amdgcn_mfma_f32_16x16x32_bf16(afl[mt], bfh[nt], a, 0, 0, 0);
                acc[mt][nt] = a;
            }
        }
        __syncthreads();
    }

    #pragma unroll
    for (int nt = 0; nt < 2; ++nt) {
        int n = n0 + wn * 32 + nt * 16 + l16;
        float bv = Bias[n];
        #pragma unroll
        for (int mt = 0; mt < 2; ++mt) {
            #pragma unroll
            for (int r = 0; r < 4; ++r) {
                int m = m0 + wm * 32 + mt * 16 + quad * 4 + r;
                Out[(size_t)m * D_MODEL + n] = acc[mt][nt][r] + bv;
            }
        }
    }
}

// ---------------------------------------------------------------------------
// Flash attention, S^T form, exp2 fixed-max softmax, q-tile 128.
// Round-5 (kept, best): 32x32x16 MFMA shape; permlane32_swap half-exchange
// for P -> PV-B-operand; setprio around MFMA clusters; dbuf 48KB; XCD remap.
// ---------------------------------------------------------------------------
__global__ __launch_bounds__(256, 3) void attn_kernel(
    const u16* __restrict__ Qhl, const u16* __restrict__ Khl, const u16* __restrict__ Vt,
    const float* __restrict__ BiasM, float* __restrict__ Opart,
    float* __restrict__ Lpart)
{
    // XCD remap: phys block p runs work w = (p%8)*96 + p/8 (bijective, 768%8==0).
    const int flat = blockIdx.x;
    const int wk   = (flat & 7) * 96 + (flat >> 3);
    const int qt   = wk & 15;             // 0..15  (fastest within group)
    const int grp  = wk >> 4;             // 0..47
    const int bh   = grp % 24;
    const int half = grp / 24;            // 0..1
    const int b    = bh / NHEAD;
    const int tid  = threadIdx.x;
    const int wave = tid >> 6, lane = tid & 63;
    const int l32  = lane & 31;           // q within wave / row within tile
    const int hi5  = lane >> 5;           // k-half selector
    const int xorv = (l32 >> 1) & 3;      // read-side swizzle term

    __shared__ u16 sK[2][4 * 2048];       // [64][32] x (hi-d0,hi-d1,lo-d0,lo-d1)
    __shared__ u16 sV[2][2 * 2048];       // [64 d][32 s] x 2

    // Q B-frags: q = qt*128 + wave*32 + l32; frag ds: d = ds*16 + hi5*8 + j
    const u16* qbase = &Qhl[((size_t)bh * SEQ + qt * 128 + wave * 32 + l32) * 128];
    bf16x8 qh[4], ql[4];
    #pragma unroll
    for (int ds = 0; ds < 4; ++ds) {
        qh[ds] = *reinterpret_cast<const bf16x8*>(&qbase[ds * 16 + hi5 * 8]);
        ql[ds] = *reinterpret_cast<const bf16x8*>(&qbase[64 + ds * 16 + hi5 * 8]);
    }

    // ones A-frag (bf16 1.0 x8) for the l row-sum MFMA
    union OU { u16 u[8]; bf16x8 v; } onesu;
    #pragma unroll
    for (int j = 0; j < 8; ++j) onesu.u[j] = 0x3F80;
    const bf16x8 ones = onesu.v;

    f32x16 oacc[2] = {};                  // O^T tiles d 0-31 / 32-63
    f32x16 lacc = {};                     // l in row 0 (all rows equal)

    const float* biasb = &BiasM[b * SEQ];
    const int strow = wave * 16 + (lane >> 2);
    const int stc8  = SRC_C8(lane);       // swizzled source column chunk
    const u16* kgb = &Khl[(size_t)bh * SEQ * 128];
    const u16* vgb = &Vt[(size_t)bh * DHEAD * SEQ];

    const int kvbeg = half * (SEQ / 2);

    // prologue: stage tile 0 into buffer 0
    #pragma unroll
    for (int j = 0; j < 4; ++j)
        stage16(&kgb[(size_t)(kvbeg + strow) * 128 + j * 32 + stc8],
                &sK[0][j * 2048 + wave * 512]);
    #pragma unroll
    for (int j = 0; j < 2; ++j)
        stage16(&vgb[(size_t)strow * SEQ + kvbeg + j * 32 + stc8],
                &sV[0][j * 2048 + wave * 512]);

    for (int it = 0; it < 16; ++it) {
        const int kv0 = kvbeg + it * 64;
        asm volatile("s_waitcnt vmcnt(0)" ::: "memory");
        __syncthreads();

        if (it + 1 < 16) {
            const int kvn = kv0 + 64;
            u16* dK = sK[(it + 1) & 1];
            u16* dV = sV[(it + 1) & 1];
            #pragma unroll
            for (int j = 0; j < 4; ++j)
                stage16(&kgb[(size_t)(kvn + strow) * 128 + j * 32 + stc8],
                        &dK[j * 2048 + wave * 512]);
            #pragma unroll
            for (int j = 0; j < 2; ++j)
                stage16(&vgb[(size_t)strow * SEQ + kvn + j * 32 + stc8],
                        &dV[j * 2048 + wave * 512]);
        }
        const u16* cK = sK[it & 1];
        const u16* cV = sV[it & 1];

        // per kv-tile: QK^T (12 mfma) -> exp2 -> pack; P kept as 8 u32/lane
        u32 pk[2][8];
        #pragma unroll
        for (int t = 0; t < 2; ++t) {
            f32x16 s;
            #pragma unroll
            for (int g = 0; g < 4; ++g) {
                float4 b4 = *reinterpret_cast<const float4*>(
                    &biasb[kv0 + t * 32 + 8 * g + 4 * hi5]);
                s[4 * g + 0] = b4.x; s[4 * g + 1] = b4.y;
                s[4 * g + 2] = b4.z; s[4 * g + 3] = b4.w;
            }
            const int rowb = (t * 32 + l32) * 32;
            __builtin_amdgcn_s_setprio(1);
            #pragma unroll
            for (int ds = 0; ds < 4; ++ds) {
                const int c8  = ((((ds & 1) * 2 + hi5) ^ xorv) * 8);
                const int off = (ds >> 1) * 2048 + rowb + c8;
                bf16x8 kh = *reinterpret_cast<const bf16x8*>(&cK[off]);
                bf16x8 kl = *reinterpret_cast<const bf16x8*>(&cK[4096 + off]);
                s = __builtin_amdgcn_mfma_f32_32x32x16_bf16(kh, qh[ds], s, 0, 0, 0);
                s = __builtin_amdgcn_mfma_f32_32x32x16_bf16(kh, ql[ds], s, 0, 0, 0);
                s = __builtin_amdgcn_mfma_f32_32x32x16_bf16(kl, qh[ds], s, 0, 0, 0);
            }
            __builtin_amdgcn_s_setprio(0);
            #pragma unroll
            for (int m = 0; m < 8; ++m)
                pk[t][m] = pack2t(exp2f(s[2 * m]), exp2f(s[2 * m + 1]));
        }

        // half-exchange: build 4 PV B-frags (kv slices of 16) from pk
        union FU { u32 u[4]; bf16x8 v; } fr[4];
        #pragma unroll
        for (int t = 0; t < 2; ++t) {
            u32 a0 = pk[t][0], b0 = pk[t][2];
            u32 a1 = pk[t][1], b1 = pk[t][3];
            u32 a2 = pk[t][4], b2 = pk[t][6];
            u32 a3 = pk[t][5], b3 = pk[t][7];
            asm volatile("v_permlane32_swap_b32 %0, %1" : "+v"(a0), "+v"(b0));
            asm volatile("v_permlane32_swap_b32 %0, %1" : "+v"(a1), "+v"(b1));
            asm volatile("v_permlane32_swap_b32 %0, %1" : "+v"(a2), "+v"(b2));
            asm volatile("v_permlane32_swap_b32 %0, %1" : "+v"(a3), "+v"(b3));
            fr[2 * t].u[0] = a0; fr[2 * t].u[1] = a1;
            fr[2 * t].u[2] = b0; fr[2 * t].u[3] = b1;
            fr[2 * t + 1].u[0] = a2; fr[2 * t + 1].u[1] = a3;
            fr[2 * t + 1].u[2] = b2; fr[2 * t + 1].u[3] = b3;
        }

        // O^T += V^T · P^T  (A = V^T frag, B = P frag), + l row-sum
        __builtin_amdgcn_s_setprio(1);
        #pragma unroll
        for (int dt = 0; dt < 2; ++dt) {
            const int drow = (dt * 32 + l32) * 32;
            #pragma unroll
            for (int sl = 0; sl < 4; ++sl) {
                const int c8  = ((((sl & 1) * 2 + hi5) ^ xorv) * 8);
                const int off = (sl >> 1) * 2048 + drow + c8;
                bf16x8 vb = *reinterpret_cast<const bf16x8*>(&cV[off]);
                oacc[dt] = __builtin_amdgcn_mfma_f32_32x32x16_bf16(vb, fr[sl].v, oacc[dt], 0, 0, 0);
            }
        }
        #pragma unroll
        for (int sl = 0; sl < 4; ++sl)
            lacc = __builtin_amdgcn_mfma_f32_32x32x16_bf16(ones, fr[sl].v, lacc, 0, 0, 0);
        __builtin_amdgcn_s_setprio(0);
        // no trailing barrier: next iteration's barrier protects the buffers
    }

    {
        size_t rowb = ((size_t)(half * (BATCH * NHEAD) + bh)) * SEQ
                    + qt * 128 + wave * 32 + l32;
        float* ob = &Opart[rowb * 64];
        #pragma unroll
        for (int dt = 0; dt < 2; ++dt) {
            #pragma unroll
            for (int g = 0; g < 4; ++g) {
                f32x4 o4 = { oacc[dt][4 * g + 0], oacc[dt][4 * g + 1],
                             oacc[dt][4 * g + 2], oacc[dt][4 * g + 3] };
                *reinterpret_cast<f32x4*>(&ob[dt * 32 + 8 * g + 4 * hi5]) = o4;
            }
        }
        if (lane < 32) Lpart[rowb] = lacc[0];   // row 0: l(q=l32)
    }
}

// ---------------------------------------------------------------------------
// attn_combine: merge 2 kv-half partials (same fixed scale -> plain sums)
// ---------------------------------------------------------------------------
__global__ void attn_combine(const float* __restrict__ Opart,
                             const float* __restrict__ Lpart,
                             u16* __restrict__ CTXh, u16* __restrict__ CTXl)
{
    const int NROW = BATCH * NHEAD * SEQ;              // 49152
    int t = blockIdx.x * 256 + threadIdx.x;
    int row = t >> 4;
    int d0 = (t & 15) << 2;
    float inv = 1.f / (Lpart[row] + Lpart[NROW + row]);
    f32x4 O0 = *reinterpret_cast<const f32x4*>(&Opart[(size_t)row * 64 + d0]);
    f32x4 O1 = *reinterpret_cast<const f32x4*>(&Opart[((size_t)NROW + row) * 64 + d0]);
    int bh = row >> 11, q = row & (SEQ - 1);
    int b = bh / NHEAD, h = bh % NHEAD;
    size_t off = ((size_t)(b * SEQ + q)) * D_MODEL + h * DHEAD + d0;
    u16x4 h4, l4;
    #pragma unroll
    for (int j = 0; j < 4; ++j) {
        float val = (O0[j] + O1[j]) * inv;
        u16 hi, lo; split2(val, hi, lo);
        h4[j] = hi; l4[j] = lo;
    }
    *reinterpret_cast<u16x4*>(&CTXh[off]) = h4;
    *reinterpret_cast<u16x4*>(&CTXl[off]) = l4;
}

// ---------------------------------------------------------------------------
extern "C" void kernel_launch(void* const* d_in, const int* in_sizes, int n_in,
                              void* d_out, int out_size, void* d_ws, size_t ws_size,
                              hipStream_t stream)
{
    const float* query = (const float*)d_in[0];
    const float* key   = (const float*)d_in[1];
    const float* value = (const float*)d_in[2];
    const int*   mask  = (const int*)d_in[3];
    const float* Wq = (const float*)d_in[4];
    const float* bq = (const float*)d_in[5];
    const float* Wk = (const float*)d_in[6];
    const float* bk = (const float*)d_in[7];
    const float* Wv = (const float*)d_in[8];
    const float* bv = (const float*)d_in[9];
    const float* Wo = (const float*)d_in[10];
    const float* bo = (const float*)d_in[11];

    char* ws = (char*)d_ws;
    const size_t P2  = (size_t)MROWS * D_MODEL * 2;       // X plane: 6.29 MB
    const size_t WP2 = (size_t)D_MODEL * D_MODEL * 2;     // W plane: 1.18 MB

    u16* Xbase = (u16*)ws;                                 // 6 planes
    u16* Xh_q = Xbase;                       u16* Xl_q = (u16*)((char*)Xh_q + P2);
    u16* Xh_k = (u16*)((char*)Xbase + 2*P2); u16* Xl_k = (u16*)((char*)Xh_k + P2);
    u16* Xh_v = (u16*)((char*)Xbase + 4*P2); u16* Xl_v = (u16*)((char*)Xh_v + P2);

    char* wtb = ws + 6 * P2;
    u16* Wh_q = (u16*)wtb;                   u16* Wl_q = (u16*)(wtb + WP2);
    u16* Wh_k = (u16*)(wtb + 2*WP2);         u16* Wl_k = (u16*)(wtb + 3*WP2);
    u16* Wh_v = (u16*)(wtb + 4*WP2);         u16* Wl_v = (u16*)(wtb + 5*WP2);
    u16* Wh_o = (u16*)(wtb + 6*WP2);         u16* Wl_o = (u16*)(wtb + 7*WP2);

    char* qb = wtb + 8 * WP2;
    const size_t QK_BYTES = (size_t)BATCH * NHEAD * SEQ * 128 * 2;  // 12.58 MB
    u16* QhlBuf = (u16*)qb;
    u16* KhlBuf = (u16*)(qb + QK_BYTES);
    u16* VtBuf  = (u16*)(qb + 2 * QK_BYTES);              // 6.29 MB

    char* tail = qb + 2 * QK_BYTES + QK_BYTES / 2;
    float* BiasM = (float*)tail;                           // 16 KB
    float* Lpart = (float*)(tail + 16384);                 // 384 KB

    float* Opart = (float*)Xh_k;          // aliases planes dead after QKV GEMM
    u16* CTXh = Xh_q; u16* CTXl = Xl_q;   // reuse query planes

    float* out = (float*)d_out;
    dim3 blk(256, 1, 1);

    prep_all<<<dim3(11536), blk, 0, stream>>>(
        query, key, value, Xbase, Wq, Wk, Wv, Wo, (u16*)wtb, mask, BiasM);

    gemm3<<<dim3(768), blk, 0, stream>>>(
        Xh_q, Xl_q, Xh_k, Xl_k, Xh_v, Xl_v,
        Wh_q, Wl_q, Wh_k, Wl_k, Wh_v, Wl_v,
        bq, bk, bv, QhlBuf, KhlBuf, VtBuf);

    attn_kernel<<<dim3(768), blk, 0, stream>>>(
        QhlBuf, KhlBuf, VtBuf, BiasM, Opart, Lpart);

    attn_combine<<<dim3(3072), blk, 0, stream>>>(Opart, Lpart, CTXh, CTXl);

    gemm_out64<<<dim3(64, 12), blk, 0, stream>>>(
        CTXh, CTXl, Wh_o, Wl_o, bo, out);
}